// Round 1
// baseline (907.914 us; speedup 1.0000x reference)
//
#include <hip/hip_runtime.h>

#define D 128
#define BM 64
#define BK 32

// ---------- CSR build ----------

__global__ void hist_kernel(const int* __restrict__ dst, int* __restrict__ cnt, int n) {
    int i = blockIdx.x * blockDim.x + threadIdx.x;
    if (i < n) atomicAdd(&cnt[dst[i]], 1);
}

// single-block hierarchical exclusive scan: 1024 threads x 8 elems/thread per pass
__global__ void scan_kernel(const int* __restrict__ cnt, int* __restrict__ off, int n) {
    __shared__ int wsum[16];
    __shared__ int carry_s;
    int t = threadIdx.x;
    int lane = t & 63, wid = t >> 6;
    if (t == 0) carry_s = 0;
    __syncthreads();
    for (int base = 0; base < n; base += 8192) {
        int i0 = base + t * 8;
        int v[8];
        int s = 0;
#pragma unroll
        for (int q = 0; q < 8; ++q) { v[q] = (i0 + q < n) ? cnt[i0 + q] : 0; s += v[q]; }
        int sc = s;
#pragma unroll
        for (int d = 1; d < 64; d <<= 1) {
            int u = __shfl_up(sc, d, 64);
            if (lane >= d) sc += u;
        }
        if (lane == 63) wsum[wid] = sc;
        __syncthreads();
        if (wid == 0) {
            int ws_ = (lane < 16) ? wsum[lane] : 0;
#pragma unroll
            for (int d = 1; d < 16; d <<= 1) {
                int u = __shfl_up(ws_, d, 64);
                if (lane >= d) ws_ += u;
            }
            if (lane < 16) wsum[lane] = ws_;
        }
        __syncthreads();
        int wbase = (wid == 0) ? 0 : wsum[wid - 1];
        int excl = carry_s + wbase + (sc - s);
#pragma unroll
        for (int q = 0; q < 8; ++q) {
            if (i0 + q < n) off[i0 + q] = excl;
            excl += v[q];
        }
        __syncthreads();
        if (t == 1023) carry_s = carry_s + wsum[15];
        __syncthreads();
    }
    if (t == 0) off[n] = carry_s;
}

__global__ void copy_kernel(const int* __restrict__ a, int* __restrict__ b, int n) {
    int i = blockIdx.x * blockDim.x + threadIdx.x;
    if (i < n) b[i] = a[i];
}

__global__ void scatter_kernel(const int* __restrict__ src, const int* __restrict__ dst,
                               int* __restrict__ cursor, int* __restrict__ sorted_src, int n) {
    int i = blockIdx.x * blockDim.x + threadIdx.x;
    if (i < n) {
        int d = dst[i];
        int p = atomicAdd(&cursor[d], 1);
        sorted_src[p] = src[i];
    }
}

// ---------- mean aggregation: one node per 128 threads, register accumulate ----------

__global__ void aggregate_kernel(const float* __restrict__ x, const int* __restrict__ off,
                                 const int* __restrict__ sorted_src, float* __restrict__ mean,
                                 int n_nodes) {
    int node = blockIdx.x * 2 + (threadIdx.x >> 7);
    int t = threadIdx.x & 127;
    if (node >= n_nodes) return;
    int beg = off[node], end = off[node + 1];
    float acc = 0.f;
    for (int e = beg; e < end; ++e) {
        int s = sorted_src[e];
        acc += x[(size_t)s * D + t];
    }
    int deg = end - beg;
    float m = acc / (float)(deg > 0 ? deg : 1);
    mean[(size_t)node * D + t] = m;
}

// ---------- fused linear: out = relu([mean||x] @ [Wl||Wr]^T + b) ----------
// fp32 tiled GEMM: BM=64 rows x 128 cols per block, K=256 in chunks of 32.

__global__ __launch_bounds__(256)
void sage_linear_kernel(const float* __restrict__ mean, const float* __restrict__ xin,
                        const float* __restrict__ Wl, const float* __restrict__ Wr,
                        const float* __restrict__ bias, float* __restrict__ out,
                        int n_nodes) {
    __shared__ float As[BM][36];   // padded: row stride 36 floats (16B-aligned, bank-spread)
    __shared__ float Bs[BK][D];

    int t = threadIdx.x;
    int tx = t & 31;      // cols tx*4 .. tx*4+3
    int ty = t >> 5;      // rows ty*8 .. ty*8+7
    int row0 = blockIdx.x * BM;

    float acc[8][4] = {};

    for (int kt = 0; kt < 8; ++kt) {
        int kbase = kt * BK;
        const float* Asrc = (kbase < D) ? mean : xin;
        const float* Wsrc = (kbase < D) ? Wl : Wr;
        int ksrc = kbase & (D - 1);

        // A tile: 64x32, 8 floats/thread
        {
            int r = t >> 2;
            int c = (t & 3) * 8;
            int gr = row0 + r;
            if (gr < n_nodes) {
                const float* p = Asrc + (size_t)gr * D + ksrc + c;
                float4 v0 = *(const float4*)(p);
                float4 v1 = *(const float4*)(p + 4);
                *(float4*)&As[r][c] = v0;
                *(float4*)&As[r][c + 4] = v1;
            } else {
#pragma unroll
                for (int q = 0; q < 8; ++q) As[r][c + q] = 0.f;
            }
        }
        // B tile: Bs[k][j] = W[j][kbase+k], 32x128, 16 floats/thread (transpose in LDS)
        {
            int j = t & 127;
            int kh = (t >> 7) * 16;
            const float* p = Wsrc + (size_t)j * D + ksrc + kh;
#pragma unroll
            for (int q = 0; q < 16; ++q) Bs[kh + q][j] = p[q];
        }
        __syncthreads();

#pragma unroll
        for (int kk = 0; kk < BK; ++kk) {
            float a[8];
#pragma unroll
            for (int r = 0; r < 8; ++r) a[r] = As[ty * 8 + r][kk];
            float4 bv = *(const float4*)&Bs[kk][tx * 4];
#pragma unroll
            for (int r = 0; r < 8; ++r) {
                acc[r][0] += a[r] * bv.x;
                acc[r][1] += a[r] * bv.y;
                acc[r][2] += a[r] * bv.z;
                acc[r][3] += a[r] * bv.w;
            }
        }
        __syncthreads();
    }

    float4 bb = *(const float4*)&bias[tx * 4];
#pragma unroll
    for (int r = 0; r < 8; ++r) {
        int gr = row0 + ty * 8 + r;
        if (gr < n_nodes) {
            float4 o;
            o.x = fmaxf(acc[r][0] + bb.x, 0.f);
            o.y = fmaxf(acc[r][1] + bb.y, 0.f);
            o.z = fmaxf(acc[r][2] + bb.z, 0.f);
            o.w = fmaxf(acc[r][3] + bb.w, 0.f);
            *(float4*)&out[(size_t)gr * D + tx * 4] = o;
        }
    }
}

extern "C" void kernel_launch(void* const* d_in, const int* in_sizes, int n_in,
                              void* d_out, int out_size, void* d_ws, size_t ws_size,
                              hipStream_t stream) {
    const float* x   = (const float*)d_in[0];
    const int*   ei  = (const int*)d_in[1];
    const float* W1l = (const float*)d_in[2];
    const float* W1r = (const float*)d_in[3];
    const float* b1  = (const float*)d_in[4];
    const float* W2l = (const float*)d_in[5];
    const float* W2r = (const float*)d_in[6];
    const float* b2  = (const float*)d_in[7];
    float* out = (float*)d_out;

    const int N = in_sizes[0] / D;
    const int E = in_sizes[1] / 2;
    const int* src = ei;
    const int* dst = ei + E;

    // workspace layout (all 16B-aligned)
    int* off_p    = (int*)d_ws;                      // N+1
    int* cnt_p    = off_p + ((N + 64) & ~15);        // N   (histogram, then cursor)
    int* sorted_p = cnt_p + ((N + 64) & ~15);        // E
    float* mean_p = (float*)(sorted_p + ((E + 63) & ~15));  // N*D

    hipMemsetAsync(cnt_p, 0, (size_t)N * sizeof(int), stream);
    hist_kernel<<<(E + 255) / 256, 256, 0, stream>>>(dst, cnt_p, E);
    scan_kernel<<<1, 1024, 0, stream>>>(cnt_p, off_p, N);
    copy_kernel<<<(N + 255) / 256, 256, 0, stream>>>(off_p, cnt_p, N);
    scatter_kernel<<<(E + 255) / 256, 256, 0, stream>>>(src, dst, cnt_p, sorted_p, E);

    // layer 1: h1 -> d_out
    aggregate_kernel<<<(N + 1) / 2, 256, 0, stream>>>(x, off_p, sorted_p, mean_p, N);
    sage_linear_kernel<<<(N + BM - 1) / BM, 256, 0, stream>>>(mean_p, x, W1l, W1r, b1, out, N);

    // layer 2: in-place on d_out (each block reads only its own rows before writing)
    aggregate_kernel<<<(N + 1) / 2, 256, 0, stream>>>(out, off_p, sorted_p, mean_p, N);
    sage_linear_kernel<<<(N + BM - 1) / BM, 256, 0, stream>>>(mean_p, out, W2l, W2r, b2, out, N);
}

// Round 2
// 590.732 us; speedup vs baseline: 1.5369x; 1.5369x over previous
//
#include <hip/hip_runtime.h>

#define D 128
#define BM 64
#define BK 32

// ---------- CSR build ----------

__global__ void hist_kernel(const int* __restrict__ dst, int* __restrict__ cnt, int n) {
    int i = blockIdx.x * blockDim.x + threadIdx.x;
    if (i < n) atomicAdd(&cnt[dst[i]], 1);
}

// single-block hierarchical exclusive scan: 1024 threads x 8 elems/thread per pass
__global__ void scan_kernel(const int* __restrict__ cnt, int* __restrict__ off, int n) {
    __shared__ int wsum[16];
    __shared__ int carry_s;
    int t = threadIdx.x;
    int lane = t & 63, wid = t >> 6;
    if (t == 0) carry_s = 0;
    __syncthreads();
    for (int base = 0; base < n; base += 8192) {
        int i0 = base + t * 8;
        int v[8];
        int s = 0;
#pragma unroll
        for (int q = 0; q < 8; ++q) { v[q] = (i0 + q < n) ? cnt[i0 + q] : 0; s += v[q]; }
        int sc = s;
#pragma unroll
        for (int d = 1; d < 64; d <<= 1) {
            int u = __shfl_up(sc, d, 64);
            if (lane >= d) sc += u;
        }
        if (lane == 63) wsum[wid] = sc;
        __syncthreads();
        if (wid == 0) {
            int ws_ = (lane < 16) ? wsum[lane] : 0;
#pragma unroll
            for (int d = 1; d < 16; d <<= 1) {
                int u = __shfl_up(ws_, d, 64);
                if (lane >= d) ws_ += u;
            }
            if (lane < 16) wsum[lane] = ws_;
        }
        __syncthreads();
        int wbase = (wid == 0) ? 0 : wsum[wid - 1];
        int excl = carry_s + wbase + (sc - s);
#pragma unroll
        for (int q = 0; q < 8; ++q) {
            if (i0 + q < n) off[i0 + q] = excl;
            excl += v[q];
        }
        __syncthreads();
        if (t == 1023) carry_s = carry_s + wsum[15];
        __syncthreads();
    }
    if (t == 0) off[n] = carry_s;
}

__global__ void copy_kernel(const int* __restrict__ a, int* __restrict__ b, int n) {
    int i = blockIdx.x * blockDim.x + threadIdx.x;
    if (i < n) b[i] = a[i];
}

__global__ void scatter_kernel(const int* __restrict__ src, const int* __restrict__ dst,
                               int* __restrict__ cursor, int* __restrict__ sorted_src, int n) {
    int i = blockIdx.x * blockDim.x + threadIdx.x;
    if (i < n) {
        int d = dst[i];
        int p = atomicAdd(&cursor[d], 1);
        sorted_src[p] = src[i];
    }
}

// ---------- mean aggregation ----------
// 32 lanes per node (float4/lane covers D=128), edge loop unrolled x8:
// 8 independent dwordx4 loads in flight per thread -> cache-BW-bound, not latency-bound.

__global__ __launch_bounds__(256)
void aggregate_kernel(const float* __restrict__ x, const int* __restrict__ off,
                      const int* __restrict__ sorted_src, float* __restrict__ mean,
                      int n_nodes) {
    int node = blockIdx.x * 8 + (threadIdx.x >> 5);
    int lane = threadIdx.x & 31;
    if (node >= n_nodes) return;
    int beg = off[node], end = off[node + 1];
    int c = lane * 4;

    float4 acc = make_float4(0.f, 0.f, 0.f, 0.f);
    int e = beg;
    for (; e + 8 <= end; e += 8) {
        const float4* p0 = (const float4*)&x[(size_t)sorted_src[e + 0] * D + c];
        const float4* p1 = (const float4*)&x[(size_t)sorted_src[e + 1] * D + c];
        const float4* p2 = (const float4*)&x[(size_t)sorted_src[e + 2] * D + c];
        const float4* p3 = (const float4*)&x[(size_t)sorted_src[e + 3] * D + c];
        const float4* p4 = (const float4*)&x[(size_t)sorted_src[e + 4] * D + c];
        const float4* p5 = (const float4*)&x[(size_t)sorted_src[e + 5] * D + c];
        const float4* p6 = (const float4*)&x[(size_t)sorted_src[e + 6] * D + c];
        const float4* p7 = (const float4*)&x[(size_t)sorted_src[e + 7] * D + c];
        float4 v0 = *p0, v1 = *p1, v2 = *p2, v3 = *p3;
        float4 v4 = *p4, v5 = *p5, v6 = *p6, v7 = *p7;
        acc.x += v0.x + v1.x + v2.x + v3.x + v4.x + v5.x + v6.x + v7.x;
        acc.y += v0.y + v1.y + v2.y + v3.y + v4.y + v5.y + v6.y + v7.y;
        acc.z += v0.z + v1.z + v2.z + v3.z + v4.z + v5.z + v6.z + v7.z;
        acc.w += v0.w + v1.w + v2.w + v3.w + v4.w + v5.w + v6.w + v7.w;
    }
    for (; e < end; ++e) {
        float4 v = *(const float4*)&x[(size_t)sorted_src[e] * D + c];
        acc.x += v.x; acc.y += v.y; acc.z += v.z; acc.w += v.w;
    }

    int deg = end - beg;
    float inv = 1.f / (float)(deg > 0 ? deg : 1);
    float4 m = make_float4(acc.x * inv, acc.y * inv, acc.z * inv, acc.w * inv);
    *(float4*)&mean[(size_t)node * D + c] = m;
}

// ---------- fused linear: out = relu([mean||x] @ [Wl||Wr]^T + b) ----------
// fp32 tiled GEMM: BM=64 rows x 128 cols per block, K=256 in chunks of 32.

__global__ __launch_bounds__(256)
void sage_linear_kernel(const float* __restrict__ mean, const float* __restrict__ xin,
                        const float* __restrict__ Wl, const float* __restrict__ Wr,
                        const float* __restrict__ bias, float* __restrict__ out,
                        int n_nodes) {
    __shared__ float As[BM][36];   // padded: row stride 36 floats (16B-aligned, bank-spread)
    __shared__ float Bs[BK][D];

    int t = threadIdx.x;
    int tx = t & 31;      // cols tx*4 .. tx*4+3
    int ty = t >> 5;      // rows ty*8 .. ty*8+7
    int row0 = blockIdx.x * BM;

    float acc[8][4] = {};

    for (int kt = 0; kt < 8; ++kt) {
        int kbase = kt * BK;
        const float* Asrc = (kbase < D) ? mean : xin;
        const float* Wsrc = (kbase < D) ? Wl : Wr;
        int ksrc = kbase & (D - 1);

        // A tile: 64x32, 8 floats/thread
        {
            int r = t >> 2;
            int c = (t & 3) * 8;
            int gr = row0 + r;
            if (gr < n_nodes) {
                const float* p = Asrc + (size_t)gr * D + ksrc + c;
                float4 v0 = *(const float4*)(p);
                float4 v1 = *(const float4*)(p + 4);
                *(float4*)&As[r][c] = v0;
                *(float4*)&As[r][c + 4] = v1;
            } else {
#pragma unroll
                for (int q = 0; q < 8; ++q) As[r][c + q] = 0.f;
            }
        }
        // B tile: Bs[k][j] = W[j][kbase+k], 32x128, 16 floats/thread (transpose in LDS)
        {
            int j = t & 127;
            int kh = (t >> 7) * 16;
            const float* p = Wsrc + (size_t)j * D + ksrc + kh;
#pragma unroll
            for (int q = 0; q < 16; ++q) Bs[kh + q][j] = p[q];
        }
        __syncthreads();

#pragma unroll
        for (int kk = 0; kk < BK; ++kk) {
            float a[8];
#pragma unroll
            for (int r = 0; r < 8; ++r) a[r] = As[ty * 8 + r][kk];
            float4 bv = *(const float4*)&Bs[kk][tx * 4];
#pragma unroll
            for (int r = 0; r < 8; ++r) {
                acc[r][0] += a[r] * bv.x;
                acc[r][1] += a[r] * bv.y;
                acc[r][2] += a[r] * bv.z;
                acc[r][3] += a[r] * bv.w;
            }
        }
        __syncthreads();
    }

    float4 bb = *(const float4*)&bias[tx * 4];
#pragma unroll
    for (int r = 0; r < 8; ++r) {
        int gr = row0 + ty * 8 + r;
        if (gr < n_nodes) {
            float4 o;
            o.x = fmaxf(acc[r][0] + bb.x, 0.f);
            o.y = fmaxf(acc[r][1] + bb.y, 0.f);
            o.z = fmaxf(acc[r][2] + bb.z, 0.f);
            o.w = fmaxf(acc[r][3] + bb.w, 0.f);
            *(float4*)&out[(size_t)gr * D + tx * 4] = o;
        }
    }
}

extern "C" void kernel_launch(void* const* d_in, const int* in_sizes, int n_in,
                              void* d_out, int out_size, void* d_ws, size_t ws_size,
                              hipStream_t stream) {
    const float* x   = (const float*)d_in[0];
    const int*   ei  = (const int*)d_in[1];
    const float* W1l = (const float*)d_in[2];
    const float* W1r = (const float*)d_in[3];
    const float* b1  = (const float*)d_in[4];
    const float* W2l = (const float*)d_in[5];
    const float* W2r = (const float*)d_in[6];
    const float* b2  = (const float*)d_in[7];
    float* out = (float*)d_out;

    const int N = in_sizes[0] / D;
    const int E = in_sizes[1] / 2;
    const int* src = ei;
    const int* dst = ei + E;

    // workspace layout (all 16B-aligned)
    int* off_p    = (int*)d_ws;                      // N+1
    int* cnt_p    = off_p + ((N + 64) & ~15);        // N   (histogram, then cursor)
    int* sorted_p = cnt_p + ((N + 64) & ~15);        // E
    float* mean_p = (float*)(sorted_p + ((E + 63) & ~15));  // N*D

    hipMemsetAsync(cnt_p, 0, (size_t)N * sizeof(int), stream);
    hist_kernel<<<(E + 255) / 256, 256, 0, stream>>>(dst, cnt_p, E);
    scan_kernel<<<1, 1024, 0, stream>>>(cnt_p, off_p, N);
    copy_kernel<<<(N + 255) / 256, 256, 0, stream>>>(off_p, cnt_p, N);
    scatter_kernel<<<(E + 255) / 256, 256, 0, stream>>>(src, dst, cnt_p, sorted_p, E);

    // layer 1: h1 -> d_out
    aggregate_kernel<<<(N + 7) / 8, 256, 0, stream>>>(x, off_p, sorted_p, mean_p, N);
    sage_linear_kernel<<<(N + BM - 1) / BM, 256, 0, stream>>>(mean_p, x, W1l, W1r, b1, out, N);

    // layer 2: in-place on d_out (each block reads only its own rows before writing)
    aggregate_kernel<<<(N + 7) / 8, 256, 0, stream>>>(out, off_p, sorted_p, mean_p, N);
    sage_linear_kernel<<<(N + BM - 1) / BM, 256, 0, stream>>>(mean_p, out, W2l, W2r, b2, out, N);
}